// Round 1
// 1449.276 us; speedup vs baseline: 1.4308x; 1.4308x over previous
//
#include <hip/hip_runtime.h>

typedef _Float16 half_t;
typedef half_t half8 __attribute__((ext_vector_type(8)));
typedef half_t half4 __attribute__((ext_vector_type(4)));
typedef float  floatx4 __attribute__((ext_vector_type(4)));

#define NB 2048
#define NT 20
#define CD 512
#define HD 1024
#define VD 2048
#define QD 1024

// 64x64 fp16 tile, LINEAR stride 64 halves (128 B) so global_load_lds can DMA
// straight into it (wave-uniform base + lane*16B; padding would break it, m104).
// ds_read_b128 bank conflicts are avoided by XOR-swizzling the 16B chunk index
// with (row & 7); the swizzle is applied by permuting the per-lane GLOBAL
// source address at stage time (m173 pattern) while LDS stays linear.
#define TILE 4096

__device__ __forceinline__ float sigmoidf_(float x) { return 1.0f / (1.0f + __expf(-x)); }
__device__ __forceinline__ float tanhf_(float x)    { return 1.0f - 2.0f / (1.0f + __expf(2.0f * x)); }
__device__ __forceinline__ float lrelu_(float x)    { return x > 0.0f ? x : 0.01f * x; }

template <int N>
__device__ __forceinline__ void zero_acc(floatx4 (&acc)[N][2][2]) {
#pragma unroll
    for (int g = 0; g < N; ++g)
#pragma unroll
        for (int a = 0; a < 2; ++a)
#pragma unroll
            for (int b = 0; b < 2; ++b)
                acc[g][a][b] = (floatx4){0.f, 0.f, 0.f, 0.f};
}

__device__ __forceinline__ void gload16(const half_t* g, half_t* l) {
    __builtin_amdgcn_global_load_lds(
        (const __attribute__((address_space(1))) void*)g,
        (__attribute__((address_space(3))) void*)l, 16, 0, 0);
}

// XCD-aware remap: all 32 m-blocks of a given weight-column block land on the
// same XCD so the per-XCD weight slice (<=1.2MB) stays L2-resident across the
// whole time loop. Requires gridDim.x % 8 == 0 (8 or 16 here), gridDim.y == 32.
__device__ __forceinline__ void xcd_remap(int& m0, int& c0) {
    const int flat = blockIdx.y * gridDim.x + blockIdx.x;
    const int xcd  = flat & 7;
    const int i    = flat >> 3;
    const int cpx  = gridDim.x >> 3;          // col-blocks per XCD (1 or 2)
    c0 = (xcd * cpx + (i >> 5)) * 64;
    m0 = (i & 31) * 64;
}

// One 64-wide K-step of MFMAs from LDS buffer lb. Gate g accumulates into
// acc[map[g]] (compile-time map -> no scratch, rule #20).
template <int NG, int NACC, int I0, int I1, int I2>
__device__ __forceinline__ void compute_tile(
    const half_t* lb, floatx4 (&acc)[NACC][2][2],
    int frow, int cb, int wr, int wc)
{
    constexpr int map[3] = {I0, I1, I2};
#pragma unroll
    for (int kk = 0; kk < 2; ++kk) {
        const int chunk = (((kk * 4 + cb) ^ (frow & 7)) * 8);
        half8 af[2];
#pragma unroll
        for (int im = 0; im < 2; ++im)
            af[im] = *(const half8*)(lb + (wr + im * 16 + frow) * 64 + chunk);
#pragma unroll
        for (int g = 0; g < NG; ++g) {
#pragma unroll
            for (int in = 0; in < 2; ++in) {
                half8 bf = *(const half8*)(lb + (1 + g) * TILE +
                                           (wc + in * 16 + frow) * 64 + chunk);
#pragma unroll
                for (int im = 0; im < 2; ++im)
                    acc[map[g]][im][in] = __builtin_amdgcn_mfma_f32_16x16x32_f16(
                        af[im], bf, acc[map[g]][im][in], 0, 0, 0);
            }
        }
    }
}

// Dual-phase pipelined GEMM: acc[map[g]] += A1[64xK1] * W1_g^T  then
// acc[mapB[g]] += A2[64xK2] * W2_g^T, flattened into one double-buffered loop:
//   stage(s+1) -> compute(s) -> __syncthreads()  (one barrier per K-step; the
// barrier's implicit vmcnt(0) drains a load issued one compute-phase earlier).
template <int NG, int NACC, int I0A, int I1A, int I2A, int I0B, int I1B, int I2B>
__device__ __forceinline__ void gemm2(
    const half_t* __restrict__ A1, int lda1, const half_t* __restrict__ W1, int gs1, int S1,
    const half_t* __restrict__ A2, int lda2, const half_t* __restrict__ W2, int gs2, int S2,
    int m0, int c0, half_t* lds, floatx4 (&acc)[NACC][2][2])
{
    const int tid  = threadIdx.x;
    const int lane = tid & 63;
    const int wid  = tid >> 6;
    const int wr   = (wid >> 1) * 32;
    const int wc   = (wid & 1) * 32;
    const int frow = lane & 15;
    const int cb   = lane >> 4;
    const int srow = tid >> 3;                       // 0..31
    const int sws  = ((tid & 7) ^ (srow & 7)) * 8;   // swizzled SOURCE chunk (halves)
    const int sdl  = srow * 64 + (tid & 7) * 8;      // linear LDS dest (halves)

    const int S = S1 + S2;
    auto stage = [&](int s, int buf) {
        const half_t* A; int lda; const half_t* W; int ldw; int gs; int k0;
        if (s < S1) { A = A1; lda = lda1; W = W1; ldw = S1 * 64; gs = gs1; k0 = s * 64; }
        else        { A = A2; lda = lda2; W = W2; ldw = S2 * 64; gs = gs2; k0 = (s - S1) * 64; }
        half_t* lb = lds + buf * (1 + NG) * TILE;
        const half_t* ga = A + (m0 + srow) * lda + k0 + sws;
        gload16(ga,            lb + sdl);
        gload16(ga + 32 * lda, lb + 32 * 64 + sdl);
#pragma unroll
        for (int g = 0; g < NG; ++g) {
            const half_t* gw = W + g * gs + (c0 + srow) * ldw + k0 + sws;
            half_t* wb = lb + (1 + g) * TILE;
            gload16(gw,            wb + sdl);
            gload16(gw + 32 * ldw, wb + 32 * 64 + sdl);
        }
    };

    stage(0, 0);
    __syncthreads();
    int cur = 0;
    for (int s = 0; s < S; ++s) {
        if (s + 1 < S) stage(s + 1, cur ^ 1);
        const half_t* lb = lds + cur * (1 + NG) * TILE;
        if (s < S1) compute_tile<NG, NACC, I0A, I1A, I2A>(lb, acc, frow, cb, wr, wc);
        else        compute_tile<NG, NACC, I0B, I1B, I2B>(lb, acc, frow, cb, wr, wc);
        __syncthreads();
        cur ^= 1;
    }
}

// fp32 -> fp16 conversion, 4 elems/thread; n must be divisible by 1024
__global__ void cvt_kernel(const float* __restrict__ src, half_t* __restrict__ dst, int n) {
    int i = (blockIdx.x * 256 + threadIdx.x) * 4;
    if (i < n) {
        float4 f = *(const float4*)(src + i);
        half4 h = {(half_t)f.x, (half_t)f.y, (half_t)f.z, (half_t)f.w};
        *(half4*)(dst + i) = h;
    }
}

// fvq = leaky(v@Wv^T) + leaky(q@Wq^T)   [NB, CD] fp32
__global__ __launch_bounds__(256, 2) void fvq_kernel(
    const half_t* __restrict__ v_h, const half_t* __restrict__ wv_w,
    const half_t* __restrict__ q_h, const half_t* __restrict__ wq_w,
    float* __restrict__ fvq)
{
    __shared__ half_t lds[4 * TILE];
    floatx4 acc[2][2][2];
    zero_acc<2>(acc);
    int m0, c0; xcd_remap(m0, c0);
    gemm2<1, 2, 0, 0, 0, 1, 0, 0>(v_h, VD, wv_w, 0, VD / 64,
                                  q_h, QD, wq_w, 0, QD / 64, m0, c0, lds, acc);

    const int lane = threadIdx.x & 63;
    const int wid = threadIdx.x >> 6;
    const int wr = (wid >> 1) * 32, wc = (wid & 1) * 32;
#pragma unroll
    for (int im = 0; im < 2; ++im)
#pragma unroll
    for (int in = 0; in < 2; ++in) {
        const int mb = m0 + wr + im * 16 + (lane >> 4) * 4;
        const int c  = c0 + wc + in * 16 + (lane & 15);
#pragma unroll
        for (int j = 0; j < 4; ++j) {
            const int m = mb + j;
            fvq[m * CD + c] = lrelu_(acc[0][im][in][j]) + lrelu_(acc[1][im][in][j]);
        }
    }
}

// step 1: h1' = GRUCell(x_t, h1); att = sigmoid(h1'*fvq)*x_t; write alphas
// acc: 0 = i_r+h_r, 1 = i_z+h_z, 2 = i_n, 3 = h_n (r/z merged across phases)
__global__ __launch_bounds__(256, 2) void step1_kernel(
    const half_t* __restrict__ cap_h,
    const half_t* __restrict__ wih1, const half_t* __restrict__ whh1,
    const float* __restrict__ b_ih1, const float* __restrict__ b_hh1,
    const half_t* __restrict__ h1_src, half_t* __restrict__ h1_dst,
    const float* __restrict__ fvq, const float* __restrict__ caption,
    const int* __restrict__ cap_len,
    half_t* __restrict__ att_h, float* __restrict__ alphas, int t)
{
    __shared__ half_t lds[8 * TILE];
    floatx4 acc[4][2][2];
    zero_acc<4>(acc);
    int m0, c0; xcd_remap(m0, c0);
    gemm2<3, 4, 0, 1, 2, 0, 1, 3>(cap_h + t * CD, NT * CD, wih1, CD * CD, CD / 64,
                                  h1_src, CD, whh1, CD * CD, CD / 64, m0, c0, lds, acc);

    const int lane = threadIdx.x & 63;
    const int wid = threadIdx.x >> 6;
    const int wr = (wid >> 1) * 32, wc = (wid & 1) * 32;
#pragma unroll
    for (int im = 0; im < 2; ++im)
#pragma unroll
    for (int in = 0; in < 2; ++in) {
        const int mb = m0 + wr + im * 16 + (lane >> 4) * 4;
        const int c  = c0 + wc + in * 16 + (lane & 15);
        const float br = b_ih1[c] + b_hh1[c];
        const float bz = b_ih1[CD + c] + b_hh1[CD + c];
        const float bin_ = b_ih1[2 * CD + c];
        const float bhn  = b_hh1[2 * CD + c];
#pragma unroll
        for (int j = 0; j < 4; ++j) {
            const int m = mb + j;
            const float r = sigmoidf_(acc[0][im][in][j] + br);
            const float z = sigmoidf_(acc[1][im][in][j] + bz);
            const float n = tanhf_(acc[2][im][in][j] + bin_ + r * (acc[3][im][in][j] + bhn));
            const float h_old = (float)h1_src[m * CD + c];
            const bool act = t < cap_len[m];
            const float h_new = act ? ((1.f - z) * n + z * h_old) : h_old;
            const float x = caption[(m * NT + t) * CD + c];
            const float at = sigmoidf_(h_new * fvq[m * CD + c]) * x;
            h1_dst[m * CD + c] = (half_t)h_new;
            att_h[m * CD + c]  = (half_t)at;
            alphas[(m * NT + t) * CD + c] = act ? at : 0.f;
        }
    }
}

// step 2: h2' = GRUCell(att, h2)
__global__ __launch_bounds__(256, 2) void step2_kernel(
    const half_t* __restrict__ att_h,
    const half_t* __restrict__ wih2, const half_t* __restrict__ whh2,
    const float* __restrict__ b_ih2, const float* __restrict__ b_hh2,
    const half_t* __restrict__ h2_src, half_t* __restrict__ h2_dst,
    const int* __restrict__ cap_len, int t)
{
    __shared__ half_t lds[8 * TILE];
    floatx4 acc[4][2][2];
    zero_acc<4>(acc);
    int m0, c0; xcd_remap(m0, c0);
    gemm2<3, 4, 0, 1, 2, 0, 1, 3>(att_h, CD, wih2, HD * CD, CD / 64,
                                  h2_src, HD, whh2, HD * HD, HD / 64, m0, c0, lds, acc);

    const int lane = threadIdx.x & 63;
    const int wid = threadIdx.x >> 6;
    const int wr = (wid >> 1) * 32, wc = (wid & 1) * 32;
#pragma unroll
    for (int im = 0; im < 2; ++im)
#pragma unroll
    for (int in = 0; in < 2; ++in) {
        const int mb = m0 + wr + im * 16 + (lane >> 4) * 4;
        const int c  = c0 + wc + in * 16 + (lane & 15);
        const float br = b_ih2[c] + b_hh2[c];
        const float bz = b_ih2[HD + c] + b_hh2[HD + c];
        const float bin_ = b_ih2[2 * HD + c];
        const float bhn  = b_hh2[2 * HD + c];
#pragma unroll
        for (int j = 0; j < 4; ++j) {
            const int m = mb + j;
            const float r = sigmoidf_(acc[0][im][in][j] + br);
            const float z = sigmoidf_(acc[1][im][in][j] + bz);
            const float n = tanhf_(acc[2][im][in][j] + bin_ + r * (acc[3][im][in][j] + bhn));
            const float h_old = (float)h2_src[m * HD + c];
            const bool act = t < cap_len[m];
            const float h_new = act ? ((1.f - z) * n + z * h_old) : h_old;
            h2_dst[m * HD + c] = (half_t)h_new;
        }
    }
}

// step 3: out = max(out, active ? leaky(h2 @ Wfc^T) : skip)
__global__ __launch_bounds__(256, 2) void step3_kernel(
    const half_t* __restrict__ h2_cur, const half_t* __restrict__ wfc,
    const int* __restrict__ cap_len, float* __restrict__ outmax, int t)
{
    __shared__ half_t lds[4 * TILE];
    floatx4 acc[1][2][2];
    zero_acc<1>(acc);
    int m0, c0; xcd_remap(m0, c0);
    gemm2<1, 1, 0, 0, 0, 0, 0, 0>(h2_cur, HD, wfc, 0, HD / 64,
                                  (const half_t*)nullptr, 0, (const half_t*)nullptr, 0, 0,
                                  m0, c0, lds, acc);

    const int lane = threadIdx.x & 63;
    const int wid = threadIdx.x >> 6;
    const int wr = (wid >> 1) * 32, wc = (wid & 1) * 32;
#pragma unroll
    for (int im = 0; im < 2; ++im)
#pragma unroll
    for (int in = 0; in < 2; ++in) {
        const int mb = m0 + wr + im * 16 + (lane >> 4) * 4;
        const int c  = c0 + wc + in * 16 + (lane & 15);
#pragma unroll
        for (int j = 0; j < 4; ++j) {
            const int m = mb + j;
            if (t < cap_len[m]) {
                const float v0 = lrelu_(acc[0][im][in][j]);
                float* p = &outmax[m * HD + c];
                *p = fmaxf(*p, v0);
            }
        }
    }
}

extern "C" void kernel_launch(void* const* d_in, const int* in_sizes, int n_in,
                              void* d_out, int out_size, void* d_ws, size_t ws_size,
                              hipStream_t stream)
{
    (void)in_sizes; (void)n_in; (void)out_size; (void)ws_size;
    const float* v     = (const float*)d_in[0];
    const float* q     = (const float*)d_in[1];
    const float* cap   = (const float*)d_in[2];
    const int*   cap_len = (const int*)d_in[3];
    const float* w_ih1 = (const float*)d_in[4];
    const float* w_hh1 = (const float*)d_in[5];
    const float* b_ih1 = (const float*)d_in[6];
    const float* b_hh1 = (const float*)d_in[7];
    const float* w_ih2 = (const float*)d_in[8];
    const float* w_hh2 = (const float*)d_in[9];
    const float* b_ih2 = (const float*)d_in[10];
    const float* b_hh2 = (const float*)d_in[11];
    const float* Wv    = (const float*)d_in[12];
    const float* Wq    = (const float*)d_in[13];
    const float* Wfc   = (const float*)d_in[14];

    float* out_max = (float*)d_out;               // [NB, HD]
    float* alphas  = (float*)d_out + (size_t)NB * HD;  // [NB, NT, CD]

    half_t* p = (half_t*)d_ws;
    half_t* v_h    = p; p += (size_t)NB * VD;
    half_t* q_h    = p; p += (size_t)NB * QD;
    half_t* cap_h  = p; p += (size_t)NB * NT * CD;
    half_t* wih1_h = p; p += 3 * CD * CD;
    half_t* whh1_h = p; p += 3 * CD * CD;
    half_t* wih2_h = p; p += 3 * HD * CD;
    half_t* whh2_h = p; p += 3 * HD * HD;
    half_t* wfc_h  = p; p += HD * HD;
    half_t* wv_h   = p; p += CD * VD;
    half_t* wq_h   = p; p += CD * QD;
    half_t* h1b[2]; h1b[0] = p; p += (size_t)NB * CD; h1b[1] = p; p += (size_t)NB * CD;
    half_t* h2b[2]; h2b[0] = p; p += (size_t)NB * HD; h2b[1] = p; p += (size_t)NB * HD;
    half_t* att_h  = p; p += (size_t)NB * CD;
    float* fvq = (float*)p;

    hipMemsetAsync(d_out, 0, (size_t)NB * HD * sizeof(float), stream);
    hipMemsetAsync(h1b[0], 0, (size_t)NB * CD * sizeof(half_t), stream);
    hipMemsetAsync(h2b[0], 0, (size_t)NB * HD * sizeof(half_t), stream);

    auto cvt = [&](const float* s, half_t* d, int n) {
        cvt_kernel<<<n / 1024, 256, 0, stream>>>(s, d, n);
    };
    cvt(v, v_h, NB * VD);
    cvt(q, q_h, NB * QD);
    cvt(cap, cap_h, NB * NT * CD);
    cvt(w_ih1, wih1_h, 3 * CD * CD);
    cvt(w_hh1, whh1_h, 3 * CD * CD);
    cvt(w_ih2, wih2_h, 3 * HD * CD);
    cvt(w_hh2, whh2_h, 3 * HD * HD);
    cvt(Wfc, wfc_h, HD * HD);
    cvt(Wv, wv_h, CD * VD);
    cvt(Wq, wq_h, CD * QD);

    fvq_kernel<<<dim3(CD / 64, NB / 64), 256, 0, stream>>>(v_h, wv_h, q_h, wq_h, fvq);

    for (int t = 0; t < NT; ++t) {
        const int s = t & 1, d = s ^ 1;
        step1_kernel<<<dim3(CD / 64, NB / 64), 256, 0, stream>>>(
            cap_h, wih1_h, whh1_h, b_ih1, b_hh1, h1b[s], h1b[d],
            fvq, cap, cap_len, att_h, alphas, t);
        step2_kernel<<<dim3(HD / 64, NB / 64), 256, 0, stream>>>(
            att_h, wih2_h, whh2_h, b_ih2, b_hh2, h2b[s], h2b[d], cap_len, t);
        step3_kernel<<<dim3(HD / 64, NB / 64), 256, 0, stream>>>(
            h2b[d], wfc_h, cap_len, out_max, t);
    }
}